// Round 18
// baseline (189.235 us; speedup 1.0000x reference)
//
#include <hip/hip_runtime.h>

#define MULV 32
#define BASE 9
#define ROW 288          // MULV*BASE
#define NPATH 11
#define W3J_SZ 729       // 9*9*9
#define PACK_STRIDE 96   // 83 nonzero packed coeffs per u, padded
#define PACK_TOTAL (MULV * PACK_STRIDE)
#define TILE 64          // edges per block (lane <-> edge)
#define QCOL 72          // columns per quarter-tile (8 u's x 9)
#define LSTR 73          // LDS row stride: bank stride 9 (coprime 32) -> conflict-free b32
#define NQ4 18           // float4s per row per quarter (QCOL/4)
#define QTOT (TILE * NQ4)  // 1152 float4s per quarter

typedef float f4a4 __attribute__((ext_vector_type(4), aligned(4)));  // dword-aligned vec4

// Path table: (i1,i2,io) blocks for IRREPS [(0,e),(1,o),(2,e)], dims {1,3,5}, offs {0,1,4}
__device__ constexpr int p_o1[NPATH] = {0,1,4, 0,1,1,4, 0,1,4,4};
__device__ constexpr int p_d1[NPATH] = {1,3,5, 1,3,3,5, 1,3,5,5};
__device__ constexpr int p_o2[NPATH] = {0,1,4, 1,0,4,1, 4,1,0,4};
__device__ constexpr int p_d2[NPATH] = {1,3,5, 3,1,5,3, 5,3,1,5};
__device__ constexpr int p_o3[NPATH] = {0,0,0, 1,1,1,1, 4,4,4,4};
__device__ constexpr int p_d3[NPATH] = {1,1,1, 3,3,3,3, 5,5,5,5};
__device__ constexpr int p_l1[NPATH] = {0,1,2, 0,1,1,2, 0,1,2,2};
__device__ constexpr int p_l2[NPATH] = {0,1,2, 1,0,2,1, 2,1,0,2};
__device__ constexpr int p_l3[NPATH] = {0,0,0, 1,1,1,1, 2,2,2,2};

// Wigner real-basis selection rules (all paths have even l1+l2+l3):
// nonzero only if #{m<0} even AND |m3| in {|m1|+|m2|, ||m1|-|m2||}.
// Necessary conditions only: a false-positive cell merely wastes an FMA on 0.0.
__device__ __host__ constexpr bool cell_nz(int p, int i, int j, int k) {
    int m1 = i - p_l1[p], m2 = j - p_l2[p], m3 = k - p_l3[p];
    if ((((m1 < 0) + (m2 < 0) + (m3 < 0)) & 1) != 0) return false;
    int a1 = m1 < 0 ? -m1 : m1, a2 = m2 < 0 ? -m2 : m2, a3 = m3 < 0 ? -m3 : m3;
    int d = a1 - a2; if (d < 0) d = -d;
    return (a3 == a1 + a2) || (a3 == d);
}
__device__ __host__ constexpr bool pair_nz(int p, int i, int j) {
    for (int k = 0; k < p_d3[p]; ++k) if (cell_nz(p, i, j, k)) return true;
    return false;
}

// ---- ws layout ----
// packed : ws[0 .. PACK_TOTAL)
// x2s    : ws + PACK_TOTAL, N*ROW floats
// count  : (int*) after x2s, N ints
// offset : count + N ; cursor : count + 2N ; bucket : count + 3N (E ints)

__global__ void zero_count_kernel(float* __restrict__ ws, const int* __restrict__ dN) {
    int N = dN[0];
    int* count = (int*)(ws + PACK_TOTAL + (long)N * ROW);
    for (int i = blockIdx.x * blockDim.x + threadIdx.x; i < N; i += gridDim.x * blockDim.x)
        count[i] = 0;
}

__global__ void hist_kernel(const int* __restrict__ idxs, float* __restrict__ ws,
                            const int* __restrict__ dN, int E) {
    int N = dN[0];
    int* count = (int*)(ws + PACK_TOTAL + (long)N * ROW);
    int t = blockIdx.x * blockDim.x + threadIdx.x;
    if (t < E) atomicAdd(&count[idxs[t]], 1);
}

// single block, 1024 threads: per-thread serial prefix (~N/1024) + one 1024-wide scan
__global__ void scan_kernel(float* __restrict__ ws, const int* __restrict__ dN) {
    int N = dN[0];
    int* count  = (int*)(ws + PACK_TOTAL + (long)N * ROW);
    int* offset = count + N;
    int* cursor = count + 2 * N;
    __shared__ int tsum[1024];
    const int tid = threadIdx.x;
    int cpt = (N + 1023) / 1024;
    int lo = tid * cpt;
    int hi = lo + cpt; if (hi > N) hi = N;
    int s = 0;
    for (int i = lo; i < hi; ++i) s += count[i];
    int v = s;
    tsum[tid] = v;
    __syncthreads();
    #pragma unroll
    for (int off = 1; off < 1024; off <<= 1) {
        int t = (tid >= off) ? tsum[tid - off] : 0;
        __syncthreads();
        v += t;
        tsum[tid] = v;
        __syncthreads();
    }
    int run = v - s;
    for (int i = lo; i < hi; ++i) {
        int c = count[i];
        offset[i] = run; cursor[i] = run;
        run += c;
    }
}

__global__ void fill_kernel(const int* __restrict__ idxs, float* __restrict__ ws,
                            const int* __restrict__ dN, int E) {
    int N = dN[0];
    int* count  = (int*)(ws + PACK_TOTAL + (long)N * ROW);
    int* cursor = count + 2 * N;
    int* bucket = count + 3 * N;
    int t = blockIdx.x * blockDim.x + threadIdx.x;
    if (t < E) {
        int n = idxs[t];
        int pos = atomicAdd(&cursor[n], 1);
        bucket[pos] = t;
    }
}

// one wave per node, 4-deep row pipeline (4 independent x2 rows in flight per wave)
__global__ __launch_bounds__(256) void gather_sum_kernel(const float* __restrict__ x2,
                                                         float* __restrict__ ws,
                                                         const int* __restrict__ dN) {
    int N = dN[0];
    float* x2s  = ws + PACK_TOTAL;
    int* count  = (int*)(x2s + (long)N * ROW);
    int* offset = count + N;
    int* bucket = count + 3 * N;
    const int lane = threadIdx.x & 63;
    const int wv   = threadIdx.x >> 6;
    for (int n0 = blockIdx.x * 4 + wv; n0 < N; n0 += gridDim.x * 4) {
        int n   = __builtin_amdgcn_readfirstlane(n0);
        int off = offset[n];
        int deg = count[n];
        float4 a0 = make_float4(0.f, 0.f, 0.f, 0.f);
        float4 a1 = make_float4(0.f, 0.f, 0.f, 0.f);
        int d = 0;
        for (; d + 4 <= deg; d += 4) {
            int e0 = bucket[off + d + 0];
            int e1 = bucket[off + d + 1];
            int e2 = bucket[off + d + 2];
            int e3 = bucket[off + d + 3];
            const float4* r0 = (const float4*)(x2 + (long)e0 * ROW);
            const float4* r1 = (const float4*)(x2 + (long)e1 * ROW);
            const float4* r2 = (const float4*)(x2 + (long)e2 * ROW);
            const float4* r3 = (const float4*)(x2 + (long)e3 * ROW);
            float4 v0 = r0[lane], v1 = r1[lane], v2 = r2[lane], v3 = r3[lane];
            float4 w0, w1, w2, w3;
            if (lane < 8) {
                w0 = r0[64 + lane]; w1 = r1[64 + lane];
                w2 = r2[64 + lane]; w3 = r3[64 + lane];
            }
            a0.x += v0.x + v1.x + v2.x + v3.x;
            a0.y += v0.y + v1.y + v2.y + v3.y;
            a0.z += v0.z + v1.z + v2.z + v3.z;
            a0.w += v0.w + v1.w + v2.w + v3.w;
            if (lane < 8) {
                a1.x += w0.x + w1.x + w2.x + w3.x;
                a1.y += w0.y + w1.y + w2.y + w3.y;
                a1.z += w0.z + w1.z + w2.z + w3.z;
                a1.w += w0.w + w1.w + w2.w + w3.w;
            }
        }
        for (; d < deg; ++d) {
            int e = bucket[off + d];
            const float4* row = (const float4*)(x2 + (long)e * ROW);
            float4 v = row[lane];
            a0.x += v.x; a0.y += v.y; a0.z += v.z; a0.w += v.w;
            if (lane < 8) {
                float4 w = row[64 + lane];
                a1.x += w.x; a1.y += w.y; a1.z += w.z; a1.w += w.w;
            }
        }
        float4* orow = (float4*)(x2s + (long)n * ROW);
        orow[lane] = a0;
        if (lane < 8) orow[64 + lane] = a1;
    }
}

// packed[u][ci] = weights[u,p] * w3j[p, cell] over nonzero cells in fixed loop order
__global__ void ww_build_kernel(const float* __restrict__ weights,
                                const float* __restrict__ w3j,
                                float* __restrict__ packed) {
    int u = threadIdx.x;
    if (u >= MULV) return;
    int ci = 0;
    #pragma unroll
    for (int p = 0; p < NPATH; ++p) {
        float wgt = weights[u * NPATH + p];
        #pragma unroll
        for (int i = 0; i < p_d1[p]; ++i)
            #pragma unroll
            for (int j = 0; j < p_d2[p]; ++j)
                #pragma unroll
                for (int k = 0; k < p_d3[p]; ++k)
                    if (cell_nz(p, i, j, k)) {
                        int idx = (p_o1[p] + i) * 81 + (p_o2[p] + j) * 9 + (p_o3[p] + k);
                        packed[u * PACK_STRIDE + ci] = wgt * w3j[p * W3J_SZ + idx];
                        ++ci;
                    }
    }
}

// Block = 256 threads = 4 waves, 64 NATURAL-ORDER edges (sequential x1/out streams)
// with BOTH operands staged in LDS per quarter. R16's failure: compute phase stalled
// on per-lane x2s reads (64 random rows, 72KB working set, prefetch depth 1). Fix:
// cooperative bulk stage of the x2s quarter-slices into a second tile (1152 float4
// loads issued together -> deep MLP, latency amortized); compute reads BOTH tiles
// from LDS at stride 73 (2-way, free). In-place morph on the x1 tile; writeout(h)
// and stage(h+1) share the thread<->(r,c) map -> 2 barriers per quarter.
template <bool GUARD>
__global__ __launch_bounds__(256, 4) void contract_kernel(
    const float* __restrict__ x1, const int* __restrict__ idxs,
    float* __restrict__ ws, const int* __restrict__ dN,
    float* __restrict__ out, int E)
{
    __shared__ float lx1[TILE * LSTR];   // 18,688 B (morphs x1 -> out)
    __shared__ float lx2[TILE * LSTR];   // 18,688 B (x2s quarter slices)
    __shared__ int ln[TILE];
    const int tid = threadIdx.x;
    const int ebase = blockIdx.x * TILE;
    const float* __restrict__ packed = ws;
    const float* __restrict__ x2s    = ws + PACK_TOTAL;

    if (tid < TILE) {
        int ee = ebase + tid;
        if (GUARD && ee >= E) ee = E - 1;
        ln[tid] = idxs[ee];
    }
    __syncthreads();

    // per-thread stage coordinates (pure arithmetic)
    int rr[5], cc4[5];
    bool ok[5];
    #pragma unroll
    for (int t = 0; t < 5; ++t) {
        int q = tid + t * 256;
        int r = q / NQ4;
        rr[t] = r; cc4[t] = q - r * NQ4;
        ok[t] = (q < QTOT) && (!GUARD || (ebase + r) < E);
    }
    int nn[5];
    #pragma unroll
    for (int t = 0; t < 5; ++t) nn[t] = ok[t] ? ln[rr[t]] : 0;

    const int lane = tid & 63;
    const int wv   = __builtin_amdgcn_readfirstlane(tid >> 6);
    const float* __restrict__ l1row = &lx1[lane * LSTR];
    const float* __restrict__ l2row = &lx2[lane * LSTR];

    #pragma unroll 1
    for (int h = 0; h < 4; ++h) {
        // stage x1 quarter (sequential rows) + x2s quarter (random rows via ln)
        #pragma unroll
        for (int t = 0; t < 5; ++t) {
            if (ok[t]) {
                float4 v = *(const float4*)(x1 + (long)(ebase + rr[t]) * ROW
                                            + h * QCOL + cc4[t] * 4);
                float* d = &lx1[rr[t] * LSTR + cc4[t] * 4];
                d[0] = v.x; d[1] = v.y; d[2] = v.z; d[3] = v.w;
            }
        }
        #pragma unroll
        for (int t = 0; t < 5; ++t) {
            if (ok[t]) {
                float4 v = *(const float4*)(x2s + (long)nn[t] * ROW
                                            + h * QCOL + cc4[t] * 4);
                float* d = &lx2[rr[t] * LSTR + cc4[t] * 4];
                d[0] = v.x; d[1] = v.y; d[2] = v.z; d[3] = v.w;
            }
        }
        __syncthreads();

        // compute 2 chunks in place (u = 8h + c*4 + wv, wave-uniform)
        #pragma unroll 1
        for (int c = 0; c < 2; ++c) {
            const int u = 8 * h + c * 4 + wv;
            const float* __restrict__ wp = packed + u * PACK_STRIDE;
            const int lbase = (c * 4 + wv) * BASE;

            float x1v[BASE], x2v[BASE], acc[BASE];
            #pragma unroll
            for (int i = 0; i < BASE; ++i) {
                x1v[i] = l1row[lbase + i];                // conflict-free b32
                x2v[i] = l2row[lbase + i];                // conflict-free b32
                acc[i] = 0.0f;
            }

            int ci = 0;
            #pragma unroll
            for (int p = 0; p < NPATH; ++p) {
                #pragma unroll
                for (int i = 0; i < p_d1[p]; ++i) {
                    #pragma unroll
                    for (int j = 0; j < p_d2[p]; ++j) {
                        if (pair_nz(p, i, j)) {
                            float xx = x1v[p_o1[p] + i] * x2v[p_o2[p] + j];
                            #pragma unroll
                            for (int k = 0; k < p_d3[p]; ++k) {
                                if (cell_nz(p, i, j, k)) {
                                    acc[p_o3[p] + k] = fmaf(wp[ci], xx, acc[p_o3[p] + k]);
                                    ++ci;
                                }
                            }
                        }
                    }
                }
            }
            float* wdst = &lx1[lane * LSTR + lbase];
            #pragma unroll
            for (int k = 0; k < BASE; ++k) wdst[k] = acc[k];   // in-place overwrite
        }
        __syncthreads();

        // write-out: sequential rows; same thread/(r,c) map as next stage -> no barrier
        #pragma unroll
        for (int t = 0; t < 5; ++t) {
            if (ok[t]) {
                const float* s = &lx1[rr[t] * LSTR + cc4[t] * 4];
                *(float4*)(out + (long)(ebase + rr[t]) * ROW + h * QCOL + cc4[t] * 4) =
                    make_float4(s[0], s[1], s[2], s[3]);
            }
        }
    }
}

extern "C" void kernel_launch(void* const* d_in, const int* in_sizes, int n_in,
                              void* d_out, int out_size, void* d_ws, size_t ws_size,
                              hipStream_t stream) {
    const float* x1      = (const float*)d_in[0];
    const float* x2      = (const float*)d_in[1];
    const int*   idxs    = (const int*)d_in[2];
    const float* weights = (const float*)d_in[3];
    const float* w3j     = (const float*)d_in[4];
    const int*   dN      = (const int*)d_in[5];
    float* out = (float*)d_out;
    float* ws  = (float*)d_ws;

    const int E = in_sizes[2];
    const int eb = (E + 255) / 256;

    // CSR build: count -> scan -> bucket fill (used by gather_sum)
    zero_count_kernel<<<256, 256, 0, stream>>>(ws, dN);
    hist_kernel<<<eb, 256, 0, stream>>>(idxs, ws, dN, E);
    scan_kernel<<<1, 1024, 0, stream>>>(ws, dN);
    fill_kernel<<<eb, 256, 0, stream>>>(idxs, ws, dN, E);

    // per-node gather-sum (4-deep row pipeline)
    gather_sum_kernel<<<2500, 256, 0, stream>>>(x2, ws, dN);

    // packed per-u nonzero coefficients (83/u)
    ww_build_kernel<<<1, 64, 0, stream>>>(weights, w3j, ws);

    // contraction: natural-order edges, dual LDS staging (x1 + x2s quarters)
    if (E % TILE == 0) {
        contract_kernel<false><<<E / TILE, 256, 0, stream>>>(x1, idxs, ws, dN, out, E);
    } else {
        contract_kernel<true><<<(E + TILE - 1) / TILE, 256, 0, stream>>>(x1, idxs, ws, dN, out, E);
    }
}

// Round 19
// 159.053 us; speedup vs baseline: 1.1898x; 1.1898x over previous
//
#include <hip/hip_runtime.h>

#define MULV 32
#define BASE 9
#define ROW 288          // MULV*BASE
#define NPATH 11
#define W3J_SZ 729       // 9*9*9
#define PACK_STRIDE 96   // 83 nonzero packed coeffs per u, padded
#define PACK_TOTAL (MULV * PACK_STRIDE)
#define TILE 64          // edges per block (lane <-> edge)
#define BLK 512          // threads per block (8 waves)
#define HCOL 144         // columns per half-tile (16 u's x 9)
#define LSTR 145         // LDS row stride: bank stride 17 (coprime 32) -> conflict-free b32
#define NH4 36           // float4s per row per half (HCOL/4)
#define HTOT (TILE * NH4)  // 2304 float4s per half

typedef float f4a4 __attribute__((ext_vector_type(4), aligned(4)));  // dword-aligned vec4

// Path table: (i1,i2,io) blocks for IRREPS [(0,e),(1,o),(2,e)], dims {1,3,5}, offs {0,1,4}
__device__ constexpr int p_o1[NPATH] = {0,1,4, 0,1,1,4, 0,1,4,4};
__device__ constexpr int p_d1[NPATH] = {1,3,5, 1,3,3,5, 1,3,5,5};
__device__ constexpr int p_o2[NPATH] = {0,1,4, 1,0,4,1, 4,1,0,4};
__device__ constexpr int p_d2[NPATH] = {1,3,5, 3,1,5,3, 5,3,1,5};
__device__ constexpr int p_o3[NPATH] = {0,0,0, 1,1,1,1, 4,4,4,4};
__device__ constexpr int p_d3[NPATH] = {1,1,1, 3,3,3,3, 5,5,5,5};
__device__ constexpr int p_l1[NPATH] = {0,1,2, 0,1,1,2, 0,1,2,2};
__device__ constexpr int p_l2[NPATH] = {0,1,2, 1,0,2,1, 2,1,0,2};
__device__ constexpr int p_l3[NPATH] = {0,0,0, 1,1,1,1, 2,2,2,2};

// Wigner real-basis selection rules (all paths have even l1+l2+l3):
// nonzero only if #{m<0} even AND |m3| in {|m1|+|m2|, ||m1|-|m2||}.
// Necessary conditions only: a false-positive cell merely wastes an FMA on 0.0.
__device__ __host__ constexpr bool cell_nz(int p, int i, int j, int k) {
    int m1 = i - p_l1[p], m2 = j - p_l2[p], m3 = k - p_l3[p];
    if ((((m1 < 0) + (m2 < 0) + (m3 < 0)) & 1) != 0) return false;
    int a1 = m1 < 0 ? -m1 : m1, a2 = m2 < 0 ? -m2 : m2, a3 = m3 < 0 ? -m3 : m3;
    int d = a1 - a2; if (d < 0) d = -d;
    return (a3 == a1 + a2) || (a3 == d);
}
__device__ __host__ constexpr bool pair_nz(int p, int i, int j) {
    for (int k = 0; k < p_d3[p]; ++k) if (cell_nz(p, i, j, k)) return true;
    return false;
}

// ---- ws layout ----
// packed : ws[0 .. PACK_TOTAL)
// x2s    : ws + PACK_TOTAL, N*ROW floats
// count  : (int*) after x2s, N ints
// offset : count + N ; cursor : count + 2N ; bucket : count + 3N (E ints)

__global__ void zero_count_kernel(float* __restrict__ ws, const int* __restrict__ dN) {
    int N = dN[0];
    int* count = (int*)(ws + PACK_TOTAL + (long)N * ROW);
    for (int i = blockIdx.x * blockDim.x + threadIdx.x; i < N; i += gridDim.x * blockDim.x)
        count[i] = 0;
}

__global__ void hist_kernel(const int* __restrict__ idxs, float* __restrict__ ws,
                            const int* __restrict__ dN, int E) {
    int N = dN[0];
    int* count = (int*)(ws + PACK_TOTAL + (long)N * ROW);
    int t = blockIdx.x * blockDim.x + threadIdx.x;
    if (t < E) atomicAdd(&count[idxs[t]], 1);
}

// single block, 1024 threads: per-thread serial prefix (~N/1024) + one 1024-wide scan
__global__ void scan_kernel(float* __restrict__ ws, const int* __restrict__ dN) {
    int N = dN[0];
    int* count  = (int*)(ws + PACK_TOTAL + (long)N * ROW);
    int* offset = count + N;
    int* cursor = count + 2 * N;
    __shared__ int tsum[1024];
    const int tid = threadIdx.x;
    int cpt = (N + 1023) / 1024;
    int lo = tid * cpt;
    int hi = lo + cpt; if (hi > N) hi = N;
    int s = 0;
    for (int i = lo; i < hi; ++i) s += count[i];
    int v = s;
    tsum[tid] = v;
    __syncthreads();
    #pragma unroll
    for (int off = 1; off < 1024; off <<= 1) {
        int t = (tid >= off) ? tsum[tid - off] : 0;
        __syncthreads();
        v += t;
        tsum[tid] = v;
        __syncthreads();
    }
    int run = v - s;
    for (int i = lo; i < hi; ++i) {
        int c = count[i];
        offset[i] = run; cursor[i] = run;
        run += c;
    }
}

__global__ void fill_kernel(const int* __restrict__ idxs, float* __restrict__ ws,
                            const int* __restrict__ dN, int E) {
    int N = dN[0];
    int* count  = (int*)(ws + PACK_TOTAL + (long)N * ROW);
    int* cursor = count + 2 * N;
    int* bucket = count + 3 * N;
    int t = blockIdx.x * blockDim.x + threadIdx.x;
    if (t < E) {
        int n = idxs[t];
        int pos = atomicAdd(&cursor[n], 1);
        bucket[pos] = t;
    }
}

// one wave per node, 4-deep row pipeline; block 0 also builds the packed coeffs
// (independent work, disjoint ws regions -> saves one launch)
__global__ __launch_bounds__(256) void gather_sum_kernel(const float* __restrict__ x2,
                                                         float* __restrict__ ws,
                                                         const int* __restrict__ dN,
                                                         const float* __restrict__ weights,
                                                         const float* __restrict__ w3j) {
    // fused ww_build: packed[u][ci] = weights[u,p] * w3j[p, cell], fixed loop order
    if (blockIdx.x == 0 && threadIdx.x < MULV) {
        int u = threadIdx.x;
        float* packed = ws;
        int ci = 0;
        #pragma unroll
        for (int p = 0; p < NPATH; ++p) {
            float wgt = weights[u * NPATH + p];
            #pragma unroll
            for (int i = 0; i < p_d1[p]; ++i)
                #pragma unroll
                for (int j = 0; j < p_d2[p]; ++j)
                    #pragma unroll
                    for (int k = 0; k < p_d3[p]; ++k)
                        if (cell_nz(p, i, j, k)) {
                            int idx = (p_o1[p] + i) * 81 + (p_o2[p] + j) * 9 + (p_o3[p] + k);
                            packed[u * PACK_STRIDE + ci] = wgt * w3j[p * W3J_SZ + idx];
                            ++ci;
                        }
        }
    }

    int N = dN[0];
    float* x2s  = ws + PACK_TOTAL;
    int* count  = (int*)(x2s + (long)N * ROW);
    int* offset = count + N;
    int* bucket = count + 3 * N;
    const int lane = threadIdx.x & 63;
    const int wv   = threadIdx.x >> 6;
    for (int n0 = blockIdx.x * 4 + wv; n0 < N; n0 += gridDim.x * 4) {
        int n   = __builtin_amdgcn_readfirstlane(n0);
        int off = offset[n];
        int deg = count[n];
        float4 a0 = make_float4(0.f, 0.f, 0.f, 0.f);
        float4 a1 = make_float4(0.f, 0.f, 0.f, 0.f);
        int d = 0;
        for (; d + 4 <= deg; d += 4) {
            int e0 = bucket[off + d + 0];
            int e1 = bucket[off + d + 1];
            int e2 = bucket[off + d + 2];
            int e3 = bucket[off + d + 3];
            const float4* r0 = (const float4*)(x2 + (long)e0 * ROW);
            const float4* r1 = (const float4*)(x2 + (long)e1 * ROW);
            const float4* r2 = (const float4*)(x2 + (long)e2 * ROW);
            const float4* r3 = (const float4*)(x2 + (long)e3 * ROW);
            float4 v0 = r0[lane], v1 = r1[lane], v2 = r2[lane], v3 = r3[lane];
            float4 w0, w1, w2, w3;
            if (lane < 8) {
                w0 = r0[64 + lane]; w1 = r1[64 + lane];
                w2 = r2[64 + lane]; w3 = r3[64 + lane];
            }
            a0.x += v0.x + v1.x + v2.x + v3.x;
            a0.y += v0.y + v1.y + v2.y + v3.y;
            a0.z += v0.z + v1.z + v2.z + v3.z;
            a0.w += v0.w + v1.w + v2.w + v3.w;
            if (lane < 8) {
                a1.x += w0.x + w1.x + w2.x + w3.x;
                a1.y += w0.y + w1.y + w2.y + w3.y;
                a1.z += w0.z + w1.z + w2.z + w3.z;
                a1.w += w0.w + w1.w + w2.w + w3.w;
            }
        }
        for (; d < deg; ++d) {
            int e = bucket[off + d];
            const float4* row = (const float4*)(x2 + (long)e * ROW);
            float4 v = row[lane];
            a0.x += v.x; a0.y += v.y; a0.z += v.z; a0.w += v.w;
            if (lane < 8) {
                float4 w = row[64 + lane];
                a1.x += w.x; a1.y += w.y; a1.z += w.z; a1.w += w.w;
            }
        }
        float4* orow = (float4*)(x2s + (long)n * ROW);
        orow[lane] = a0;
        if (lane < 8) orow[64 + lane] = a1;
    }
}

// Block = 512 threads = 8 waves, 64 CSR-ordered edges, half-tiles (576B granules).
// XCD-bijective blockIdx swizzle: consecutive CSR blocks (which share x2s node rows)
// co-locate on one XCD; each XCD's x2s working slice (~1.4MB) then fits its private
// 4MB L2. u = 16h + cc*8 + wv stays wave-uniform -> s_load coeffs. In-place LDS
// morph x1 -> out; writeout(h)/stage(h+1) share thread<->(r,c) map -> 2 barriers/half.
template <bool GUARD>
__global__ __launch_bounds__(512, 4) void contract_kernel(
    const float* __restrict__ x1, const int* __restrict__ idxs,
    float* __restrict__ ws, const int* __restrict__ dN,
    float* __restrict__ out, int E)
{
    __shared__ float tile[TILE * LSTR];   // 37,120 B
    __shared__ int lperm[TILE];
    const int tid = threadIdx.x;

    // bijective XCD swizzle (m204 form): blocks with equal (bid&7) cover a
    // contiguous work range -> per-XCD L2 locality for x2s
    const int nwg = gridDim.x;
    const int q   = nwg >> 3, rm = nwg & 7;
    const int xcd = blockIdx.x & 7, idx0 = blockIdx.x >> 3;
    const int wid = (xcd < rm ? xcd * (q + 1) : rm * (q + 1) + (xcd - rm) * q) + idx0;

    const long ebase = (long)wid * TILE;
    const float* __restrict__ packed = ws;
    const float* __restrict__ x2s    = ws + PACK_TOTAL;
    const int N = dN[0];
    const int* __restrict__ bucket = (const int*)(x2s + (long)N * ROW) + 3 * N;

    if (tid < TILE) {
        long ee = ebase + tid;
        lperm[tid] = (!GUARD || ee < (long)E) ? bucket[ee] : -1;
    }
    __syncthreads();

    const int lane = tid & 63;
    const int wv   = __builtin_amdgcn_readfirstlane(tid >> 6);
    const int e    = lperm[lane];
    const int n    = idxs[e >= 0 ? e : 0];
    const float* __restrict__ r2 = x2s + (long)n * ROW;
    float* __restrict__ lrow = &tile[lane * LSTR];

    // prefetch chunk 0's x2 slice (u = wv)
    float x2c[BASE];
    {
        const float* s = r2 + wv * BASE;
        f4a4 a = *(const f4a4*)s;
        f4a4 b = *(const f4a4*)(s + 4);
        x2c[0]=a.x; x2c[1]=a.y; x2c[2]=a.z; x2c[3]=a.w;
        x2c[4]=b.x; x2c[5]=b.y; x2c[6]=b.z; x2c[7]=b.w;
        x2c[8]=s[8];
    }

    #pragma unroll 1
    for (int h = 0; h < 2; ++h) {
        // stage half-tile: 64 rows x 36 float4, coalesced within rows
        for (int qq = tid; qq < HTOT; qq += BLK) {
            int r = qq / NH4, c = qq - r * NH4;
            int er = lperm[r];
            if (!GUARD || er >= 0) {
                float4 v = *(const float4*)(x1 + (long)er * ROW + h * HCOL + c * 4);
                float* d = &tile[r * LSTR + c * 4];
                d[0] = v.x; d[1] = v.y; d[2] = v.z; d[3] = v.w;
            }
        }
        __syncthreads();

        // compute 2 chunks in place (m = 2h + cc, u = m*8 + wv, wave-uniform)
        #pragma unroll 1
        for (int cc = 0; cc < 2; ++cc) {
            const int m = 2 * h + cc;
            const int u = m * 8 + wv;
            const float* __restrict__ wp = packed + u * PACK_STRIDE;

            // prefetch next chunk's x2 slice (u+8) while computing this one
            float x2n[BASE];
            if (m < 3) {
                const float* s = r2 + (u + 8) * BASE;
                f4a4 a = *(const f4a4*)s;
                f4a4 b = *(const f4a4*)(s + 4);
                x2n[0]=a.x; x2n[1]=a.y; x2n[2]=a.z; x2n[3]=a.w;
                x2n[4]=b.x; x2n[5]=b.y; x2n[6]=b.z; x2n[7]=b.w;
                x2n[8]=s[8];
            }

            const int lbase = (cc * 8 + wv) * BASE;       // offset within half row
            float x1v[BASE], acc[BASE];
            #pragma unroll
            for (int i = 0; i < BASE; ++i) {
                x1v[i] = lrow[lbase + i];                 // conflict-free b32 (stride 145)
                acc[i] = 0.0f;
            }

            int ci = 0;
            #pragma unroll
            for (int p = 0; p < NPATH; ++p) {
                #pragma unroll
                for (int i = 0; i < p_d1[p]; ++i) {
                    #pragma unroll
                    for (int j = 0; j < p_d2[p]; ++j) {
                        if (pair_nz(p, i, j)) {
                            float xx = x1v[p_o1[p] + i] * x2c[p_o2[p] + j];
                            #pragma unroll
                            for (int k = 0; k < p_d3[p]; ++k) {
                                if (cell_nz(p, i, j, k)) {
                                    acc[p_o3[p] + k] = fmaf(wp[ci], xx, acc[p_o3[p] + k]);
                                    ++ci;
                                }
                            }
                        }
                    }
                }
            }
            #pragma unroll
            for (int k = 0; k < BASE; ++k)
                lrow[lbase + k] = acc[k];                 // in-place overwrite
            if (m < 3) {
                #pragma unroll
                for (int i = 0; i < BASE; ++i) x2c[i] = x2n[i];
            }
        }
        __syncthreads();

        // writeout: same thread touches the same tile (r,c) it stages next half ->
        // no barrier needed between writeout(h) and stage(h+1)
        for (int qq = tid; qq < HTOT; qq += BLK) {
            int r = qq / NH4, c = qq - r * NH4;
            int er = lperm[r];
            if (!GUARD || er >= 0) {
                const float* s = &tile[r * LSTR + c * 4];
                *(float4*)(out + (long)er * ROW + h * HCOL + c * 4) =
                    make_float4(s[0], s[1], s[2], s[3]);
            }
        }
    }
}

extern "C" void kernel_launch(void* const* d_in, const int* in_sizes, int n_in,
                              void* d_out, int out_size, void* d_ws, size_t ws_size,
                              hipStream_t stream) {
    const float* x1      = (const float*)d_in[0];
    const float* x2      = (const float*)d_in[1];
    const int*   idxs    = (const int*)d_in[2];
    const float* weights = (const float*)d_in[3];
    const float* w3j     = (const float*)d_in[4];
    const int*   dN      = (const int*)d_in[5];
    float* out = (float*)d_out;
    float* ws  = (float*)d_ws;

    const int E = in_sizes[2];
    const int eb = (E + 255) / 256;

    // CSR build: count -> scan -> bucket fill
    zero_count_kernel<<<256, 256, 0, stream>>>(ws, dN);
    hist_kernel<<<eb, 256, 0, stream>>>(idxs, ws, dN, E);
    scan_kernel<<<1, 1024, 0, stream>>>(ws, dN);
    fill_kernel<<<eb, 256, 0, stream>>>(idxs, ws, dN, E);

    // per-node gather-sum (4-deep row pipeline) + fused ww_build
    gather_sum_kernel<<<2500, 256, 0, stream>>>(x2, ws, dN, weights, w3j);

    // contraction: CSR-ordered, half-tiles, XCD-swizzled, 512-thread blocks
    if (E % TILE == 0) {
        contract_kernel<false><<<E / TILE, BLK, 0, stream>>>(x1, idxs, ws, dN, out, E);
    } else {
        contract_kernel<true><<<(E + TILE - 1) / TILE, BLK, 0, stream>>>(x1, idxs, ws, dN, out, E);
    }
}